// Round 4
// baseline (233.824 us; speedup 1.0000x reference)
//
#include <hip/hip_runtime.h>

// MHA: B=2, S=2048, D=1024, H=16, DK=64. All GEMMs are x @ W.T (+bias).
// R12: attn de-lockstepped. R9/R10/R11 all flat at ~51.5us with MfmaUtil
//  pinned at 26% -> ~60% of wall is stall: every wave on the GPU runs the
//  same loop with per-iter barriers, so all pipes phase-align (global QK
//  phase, global exp phase...). Fix: ZERO barriers in the main loop. Each
//  wave owns PRIVATE double-buffered K/V chunks (32keys x 64d and 64d x
//  32keys, 4 KB each), stages them itself with global_load_lds, and syncs
//  only on its own counted s_waitcnt vmcnt(8). K/V staged 2x (wq-pair
//  duplication, 2nd read L2-hit). Waves drift -> exp of one overlaps MFMA
//  of another. Also: grid transposed to (bh,qblk) so one bh's 16 q-blocks
//  share an XCD (K/V panel L2-resident: 4 panels x 512KB = 2MB < 4MB L2).
//  LDS 64 KB/block, 2 blocks/CU. swap23/XOR-swizzle/register-P unchanged.

#define S_LEN 2048
#define BATCH 2
#define DM    1024
#define NH    16
#define DKH   64
#define BS    (BATCH * S_LEN)   // 4096 rows

typedef _Float16 f16x8 __attribute__((ext_vector_type(8)));
typedef _Float16 f16x4 __attribute__((ext_vector_type(4)));
typedef _Float16 f16x2 __attribute__((ext_vector_type(2)));
typedef __fp16   h16x2 __attribute__((ext_vector_type(2)));
typedef float    f32x4 __attribute__((ext_vector_type(4)));
typedef float    f32x16 __attribute__((ext_vector_type(16)));

__device__ __forceinline__ f16x2 pk_f16(float a, float b) {
  h16x2 r = __builtin_amdgcn_cvt_pkrtz(a, b);
  return __builtin_bit_cast(f16x2, r);
}

__device__ __forceinline__ void gld16(const void* g, void* l) {
  __builtin_amdgcn_global_load_lds(
      (const __attribute__((address_space(1))) void*)g,
      (__attribute__((address_space(3))) void*)l, 16, 0, 0);
}

__device__ __forceinline__ float fast_exp2(float x) {
#if __has_builtin(__builtin_amdgcn_exp2f)
  return __builtin_amdgcn_exp2f(x);
#else
  return exp2f(x);
#endif
}

__device__ __forceinline__ int swap23(int x) {   // swap bits 2 and 3 (involution)
  return (x & ~12) | ((x & 4) << 1) | ((x & 8) >> 1);
}

// ---------------- fp32 -> fp16 conversion ----------------
__global__ __launch_bounds__(256) void cvt_all(
    const float* __restrict__ q, const float* __restrict__ k, const float* __restrict__ v,
    const float* __restrict__ wq, const float* __restrict__ wk,
    const float* __restrict__ wv, const float* __restrict__ wo,
    _Float16* __restrict__ xq, _Float16* __restrict__ xk, _Float16* __restrict__ xv,
    _Float16* __restrict__ w16)
{
  const int y = blockIdx.y;
  const float* src; _Float16* dst; int n;
  if (y == 0)      { src = q;  dst = xq; n = BS * DM; }
  else if (y == 1) { src = k;  dst = xk; n = BS * DM; }
  else if (y == 2) { src = v;  dst = xv; n = BS * DM; }
  else {
    src = (y == 3) ? wq : ((y == 4) ? wk : ((y == 5) ? wv : wo));
    dst = w16 + (size_t)(y - 3) * (DM * DM);
    n = DM * DM;
  }
  int i0 = (blockIdx.x * 256 + threadIdx.x) * 4;
  if (i0 < n) {
    float4 f = *(const float4*)(src + i0);
    f16x2 lo = pk_f16(f.x, f.y);
    f16x2 hi = pk_f16(f.z, f.w);
    f16x4 hh; hh[0] = lo[0]; hh[1] = lo[1]; hh[2] = hi[0]; hh[3] = hi[1];
    *(f16x4*)(dst + i0) = hh;
  }
}

// ---------------- 128x128-tile GEMM: C = (A @ W^T + bias)*oscale ----------------
template <typename OUT_T, bool VT>
__device__ __forceinline__ void gemm_core(
    const _Float16* __restrict__ A, const _Float16* __restrict__ W,
    const float* __restrict__ bias, OUT_T* __restrict__ out, float oscale)
{
  const int tid  = threadIdx.x;
  const int l    = tid & 63;
  const int wv   = tid >> 6;
  const int c    = l & 15, quad = l >> 4;
  const int m0   = blockIdx.y * 128, n0 = blockIdx.x * 128;
  const int wm   = wv & 1, wn = wv >> 1;
  __shared__ _Float16 sA[128 * 64];
  __shared__ _Float16 sB[128 * 64];

  const _Float16* gA[4]; const _Float16* gB[4];
#pragma unroll
  for (int p = 0; p < 4; ++p) {
    int s = tid + p * 256, r = s >> 3, g = (s & 7) ^ (r & 7);
    gA[p] = A + (size_t)(m0 + r) * DM + g * 8;
    gB[p] = W + (size_t)(n0 + r) * DM + g * 8;
  }
  const int cx = c & 7;

  f32x4 acc[4][4] = {};
  for (int k0 = 0; k0 < DM; k0 += 64) {
    __syncthreads();
#pragma unroll
    for (int p = 0; p < 4; ++p) {
      gld16(gA[p] + k0, sA + (tid + p * 256) * 8);
      gld16(gB[p] + k0, sB + (tid + p * 256) * 8);
    }
    __syncthreads();
#pragma unroll
    for (int ks = 0; ks < 2; ++ks) {
      f16x8 af[4], bf[4];
#pragma unroll
      for (int i = 0; i < 4; ++i)
        af[i] = *(const f16x8*)&sA[(wm * 64 + i * 16 + c) * 64 + ((ks * 4 + quad) ^ cx) * 8];
#pragma unroll
      for (int j = 0; j < 4; ++j)
        bf[j] = *(const f16x8*)&sB[(wn * 64 + j * 16 + c) * 64 + ((ks * 4 + quad) ^ cx) * 8];
#pragma unroll
      for (int i = 0; i < 4; ++i)
#pragma unroll
        for (int j = 0; j < 4; ++j)
          acc[i][j] = __builtin_amdgcn_mfma_f32_16x16x32_f16(af[i], bf[j], acc[i][j], 0, 0, 0);
    }
  }
  if constexpr (VT) {
#pragma unroll
    for (int j = 0; j < 4; ++j) {
      int col = n0 + wn * 64 + j * 16 + c;
      float bb = bias[col];
      int hh = col >> 6, dd = col & 63;
#pragma unroll
      for (int i = 0; i < 4; ++i) {
        int row = m0 + wm * 64 + i * 16 + quad * 4;
        int bb2 = row >> 11, ss = row & (S_LEN - 1);
        _Float16* dst = (_Float16*)out + ((size_t)(bb2 * NH + hh) * DKH + dd) * S_LEN + ss;
        f16x4 v4;
#pragma unroll
        for (int r = 0; r < 4; ++r) v4[r] = (_Float16)((acc[i][j][r] + bb) * oscale);
        *(f16x4*)dst = v4;
      }
    }
  } else {
#pragma unroll
    for (int j = 0; j < 4; ++j) {
      int col = n0 + wn * 64 + j * 16 + c;
      float bb = bias[col];
#pragma unroll
      for (int i = 0; i < 4; ++i) {
        int row = m0 + wm * 64 + i * 16 + quad * 4;
#pragma unroll
        for (int r = 0; r < 4; ++r) {
          float vv = (acc[i][j][r] + bb) * oscale;
          out[(size_t)(row + r) * DM + col] = (OUT_T)vv;
        }
      }
    }
  }
}

#define SC_Q (0.125f * 1.44269504088896340736f)   // 1/sqrt(64) * log2(e)

__global__ __launch_bounds__(256) void proj3(
    const _Float16* __restrict__ xq, const _Float16* __restrict__ xk,
    const _Float16* __restrict__ xv, const _Float16* __restrict__ w16,
    const float* __restrict__ bq, const float* __restrict__ bk, const float* __restrict__ bv,
    _Float16* __restrict__ Q, _Float16* __restrict__ K, _Float16* __restrict__ Vt)
{
  const int z = blockIdx.z;
  if (z == 2) {
    gemm_core<_Float16, true>(xv, w16 + (size_t)2 * DM * DM, bv, Vt, 1.0f);
  } else if (z == 0) {
    gemm_core<_Float16, false>(xq, w16, bq, Q, SC_Q);
  } else {
    gemm_core<_Float16, false>(xk, w16 + (size_t)DM * DM, bk, K, 1.0f);
  }
}

__global__ __launch_bounds__(256) void out_gemm(
    const _Float16* __restrict__ ctx, const _Float16* __restrict__ wo,
    const float* __restrict__ bo, float* __restrict__ out)
{
  gemm_core<float, false>(ctx, wo, bo, out, 1.0f);
}

// ---------------- fused flash attention (32x32 MFMA, register-resident P) -----
// R12: grid (B*H, S/128) = (32, 16) -- bh fastest so one bh's q-blocks share
// an XCD. 4 waves = (wq in 2) x (wk in 2); wave owns 64 q x 32 keys/iter with
// PRIVATE double-buffered K/V chunks in LDS. NO barriers in the main loop:
// per-wave counted s_waitcnt vmcnt(8) only. One __syncthreads before the
// cross-wave epilogue merge.
__global__ __launch_bounds__(256, 2) void attn(
    const _Float16* __restrict__ Q, const _Float16* __restrict__ K,
    const _Float16* __restrict__ Vt, _Float16* __restrict__ ctx)
{
  const int tid = threadIdx.x;
  const int l   = tid & 63, wv = tid >> 6;
  const int lo5 = l & 31, hf = l >> 5;
  const int wq  = wv >> 1, wk = wv & 1;
  const int bh  = blockIdx.x;          // XCD-local: id%8 == bh%8
  const int q0  = blockIdx.y * 128;
  const int b   = bh >> 4, hd = bh & 15;

  // per-wave private chunks, double-buffered. K: [32 key-rows][64 d] swizzled
  // 16B blocks (8/row, XOR row&7), rows permuted by swap23. V: [64 d][32 keys]
  // swizzled 16B blocks (4/row, XOR row&3), natural d.
  __shared__ _Float16 sKw[4][2][32 * 64];
  __shared__ _Float16 sVw[4][2][64 * 32];

  // persistent Q B-frags: qf[qb][kc] = Q[q = q0+wq*64+qb*32+lo5][d = 16*kc+8*hf ..+8]
  f16x8 qf0[4], qf1[4];
  {
    const _Float16* Qg0 = Q + ((size_t)(b * S_LEN + q0 + wq * 64 + lo5)) * DM + hd * DKH + 8 * hf;
    const _Float16* Qg1 = Qg0 + (size_t)32 * DM;
#pragma unroll
    for (int kc = 0; kc < 4; ++kc) { qf0[kc] = *(const f16x8*)(Qg0 + 16 * kc);
                                     qf1[kc] = *(const f16x8*)(Qg1 + 16 * kc); }
  }

  f32x16 o0[2] = {}, o1[2] = {};
  float l0 = 0.f, l1 = 0.f;
  const f16x2 ones = {(_Float16)1.0f, (_Float16)1.0f};

  const _Float16* Kg0 = K + ((size_t)b * S_LEN) * DM + hd * DKH;
  const _Float16* Vg0 = Vt + ((size_t)bh * DKH) * S_LEN;

  // staging address precompute (per lane, 4 slots each for K and V).
  // K slot s = p*64+l: row r=s>>3 (0..31), LDS blk pos = s&7 holds logical
  //   d-block (s&7)^(r&7); global key row = 32*wk + swap23(r).
  // V slot s = p*64+l: d-row r=s>>2 (0..63), LDS blk pos = s&3 holds logical
  //   key-block (s&3)^(r&3); global key col = 32*wk + ((s&3)^(r&3))*8.
  const _Float16* gK[4]; const _Float16* gV[4];
#pragma unroll
  for (int p = 0; p < 4; ++p) {
    int s  = p * 64 + l;
    int rk = s >> 3, gk = (s & 7) ^ (rk & 7);
    gK[p] = Kg0 + (size_t)(32 * wk + swap23(rk)) * DM + gk * 8;
    int rv = s >> 2, lv = (s & 3) ^ (rv & 3);
    gV[p] = Vg0 + (size_t)rv * S_LEN + 32 * wk + lv * 8;
  }
  const int rx7 = lo5 & 7;   // K frag-read block xor
  const int rx3 = lo5 & 3;   // V frag-read block xor

  _Float16* kA = &sKw[wv][0][0]; _Float16* kB = &sKw[wv][1][0];
  _Float16* vA = &sVw[wv][0][0]; _Float16* vB = &sVw[wv][1][0];

  // stage tile t into (dK, dV): 8 gld_lds, LDS dst = base + lane*16B pattern
#define STAGE(t, dK, dV) do {                               \
    const size_t o = (size_t)(t) * 64;                      \
    gld16(gK[0] + o * DM, (dK) + (l +   0) * 8);            \
    gld16(gK[1] + o * DM, (dK) + (l +  64) * 8);            \
    gld16(gK[2] + o * DM, (dK) + (l + 128) * 8);            \
    gld16(gK[3] + o * DM, (dK) + (l + 192) * 8);            \
    gld16(gV[0] + o,      (dV) + (l +   0) * 8);            \
    gld16(gV[1] + o,      (dV) + (l +  64) * 8);            \
    gld16(gV[2] + o,      (dV) + (l + 128) * 8);            \
    gld16(gV[3] + o,      (dV) + (l + 192) * 8);            \
  } while (0)

  // prologue: tile 0 -> buffer A (8 loads in flight)
  STAGE(0, kA, vA);

  const int NT = S_LEN / 64;
  for (int kt = 0; kt < NT; ++kt) {
    // issue next tile into the spare buffer (this wave finished reading it
    // last iteration; no other wave touches it)
    if (kt + 1 < NT) {
      STAGE(kt + 1, kB, vB);
      asm volatile("s_waitcnt vmcnt(8)" ::: "memory");  // tile kt landed; kt+1 in flight
    } else {
      asm volatile("s_waitcnt vmcnt(0)" ::: "memory");
    }

    // S^T for this wave's 32-key chunk vs both q-blocks (2 indep chains)
    f32x16 sA0 = {}, sA1 = {};
    __builtin_amdgcn_s_setprio(1);
#pragma unroll
    for (int kc = 0; kc < 4; ++kc) {
      f16x8 kf = *(const f16x8*)&kA[lo5 * 64 + ((2 * kc + hf) ^ rx7) * 8];
      sA0 = __builtin_amdgcn_mfma_f32_32x32x16_f16(kf, qf0[kc], sA0, 0, 0, 0);
      sA1 = __builtin_amdgcn_mfma_f32_32x32x16_f16(kf, qf1[kc], sA1, 0, 0, 0);
    }
    __builtin_amdgcn_s_setprio(0);

    // P = 2^S, packed fp16 in C-reg order -> direct PV A-operand (swap23).
    f16x8 p0[2], p1[2];
#pragma unroll
    for (int half = 0; half < 2; ++half)
#pragma unroll
      for (int j2 = 0; j2 < 4; ++j2) {
        float a0 = fast_exp2(sA0[8 * half + 2 * j2]);
        float a1 = fast_exp2(sA0[8 * half + 2 * j2 + 1]);
        f16x2 pka = pk_f16(a0, a1);
        p0[half][2 * j2]     = pka[0];
        p0[half][2 * j2 + 1] = pka[1];
        l0 = __builtin_amdgcn_fdot2(__builtin_bit_cast(h16x2, pka),
                                    __builtin_bit_cast(h16x2, ones), l0, false);
        float b0 = fast_exp2(sA1[8 * half + 2 * j2]);
        float b1 = fast_exp2(sA1[8 * half + 2 * j2 + 1]);
        f16x2 pkb = pk_f16(b0, b1);
        p1[half][2 * j2]     = pkb[0];
        p1[half][2 * j2 + 1] = pkb[1];
        l1 = __builtin_amdgcn_fdot2(__builtin_bit_cast(h16x2, pkb),
                                    __builtin_bit_cast(h16x2, ones), l1, false);
      }

    // PV: one vf read feeds both q-blocks' O accumulators.
    __builtin_amdgcn_s_setprio(1);
#pragma unroll
    for (int db = 0; db < 2; ++db)
#pragma unroll
      for (int half = 0; half < 2; ++half) {
        f16x8 vf = *(const f16x8*)&vA[(32 * db + lo5) * 32 + ((2 * half + hf) ^ rx3) * 8];
        o0[db] = __builtin_amdgcn_mfma_f32_32x32x16_f16(p0[half], vf, o0[db], 0, 0, 0);
        o1[db] = __builtin_amdgcn_mfma_f32_32x32x16_f16(p1[half], vf, o1[db], 0, 0, 0);
      }
    __builtin_amdgcn_s_setprio(0);

    // swap private buffers (register renaming only)
    _Float16* t0 = kA; kA = kB; kB = t0;
    _Float16* t1 = vA; vA = vB; vB = t1;
  }
#undef STAGE

  __syncthreads();   // all waves done computing; LDS dead -> merge scratch

  // per-wave row sums (partial over wk's 32 keys), combined across halves
  l0 += __shfl_xor(l0, 32);
  l1 += __shfl_xor(l1, 32);
  float* lbuf = (float*)&sVw[0][0][0];  // [wq][qb][wk][32] = 256 floats
  float* obuf = (float*)&sKw[0][0][0];  // 16 KB f32 scratch per db pass
  if (hf == 0) {
    lbuf[((wq * 2 + 0) * 2 + wk) * 32 + lo5] = l0;
    lbuf[((wq * 2 + 1) * 2 + wk) * 32 + lo5] = l1;
  }
  __syncthreads();

  float inv0[16], inv1[16];
#pragma unroll
  for (int r = 0; r < 16; ++r) {
    int qq = 8 * (r >> 2) + 4 * hf + (r & 3);
    inv0[r] = 1.0f / (lbuf[((wq * 2 + 0) * 2 + 0) * 32 + qq] +
                      lbuf[((wq * 2 + 0) * 2 + 1) * 32 + qq]);
    inv1[r] = 1.0f / (lbuf[((wq * 2 + 1) * 2 + 0) * 32 + qq] +
                      lbuf[((wq * 2 + 1) * 2 + 1) * 32 + qq]);
  }

  _Float16* Og = ctx + ((size_t)(b * S_LEN + q0 + wq * 64)) * DM + hd * DKH;
#pragma unroll
  for (int db = 0; db < 2; ++db) {
    // pass: wk==1 publishes its partial o[.][db]; wk==0 adds + stores
    if (wk == 1) {
#pragma unroll
      for (int r = 0; r < 16; ++r) {
        int qq = 8 * (r >> 2) + 4 * hf + (r & 3);
        obuf[((wq * 2 + 0) * 32 + qq) * 32 + lo5] = o0[db][r];
        obuf[((wq * 2 + 1) * 32 + qq) * 32 + lo5] = o1[db][r];
      }
    }
    __syncthreads();
    if (wk == 0) {
#pragma unroll
      for (int r = 0; r < 16; ++r) {
        int qq = 8 * (r >> 2) + 4 * hf + (r & 3);
        float v0 = o0[db][r] + obuf[((wq * 2 + 0) * 32 + qq) * 32 + lo5];
        float v1 = o1[db][r] + obuf[((wq * 2 + 1) * 32 + qq) * 32 + lo5];
        Og[(size_t)qq * DM + 32 * db + lo5]        = (_Float16)(v0 * inv0[r]);
        Og[(size_t)(32 + qq) * DM + 32 * db + lo5] = (_Float16)(v1 * inv1[r]);
      }
    }
    __syncthreads();   // obuf free for next db pass
  }
}

extern "C" void kernel_launch(void* const* d_in, const int* in_sizes, int n_in,
                              void* d_out, int out_size, void* d_ws, size_t ws_size,
                              hipStream_t stream)
{
  (void)in_sizes; (void)n_in; (void)out_size; (void)ws_size;
  const float* q  = (const float*)d_in[0];
  const float* k  = (const float*)d_in[1];
  const float* v  = (const float*)d_in[2];
  const float* wq = (const float*)d_in[3];
  const float* bq = (const float*)d_in[4];
  const float* wk = (const float*)d_in[5];
  const float* bk = (const float*)d_in[6];
  const float* wv = (const float*)d_in[7];
  const float* bv = (const float*)d_in[8];
  const float* wo = (const float*)d_in[9];
  const float* bo = (const float*)d_in[10];

  char* ws = (char*)d_ws;
  _Float16* XQ  = (_Float16*)(ws);                    // dead after proj3 -> CTX
  _Float16* XK  = (_Float16*)(ws + (8u  << 20));
  _Float16* XV  = (_Float16*)(ws + (16u << 20));
  _Float16* W16 = (_Float16*)(ws + (24u << 20));      // Wq,Wk,Wv,Wo
  _Float16* Qp  = (_Float16*)(ws + (32u << 20));
  _Float16* Kp  = (_Float16*)(ws + (40u << 20));
  _Float16* VT  = (_Float16*)(ws + (48u << 20));      // proj3 writes transposed V here
  _Float16* CTX = XQ;
  float* out = (float*)d_out;

  cvt_all<<<dim3(4096, 7), 256, 0, stream>>>(q, k, v, wq, wk, wv, wo, XQ, XK, XV, W16);
  proj3<<<dim3(8, 32, 3), 256, 0, stream>>>(XQ, XK, XV, W16, bq, bk, bv, Qp, Kp, VT);
  attn<<<dim3(32, 16), 256, 0, stream>>>(Qp, Kp, VT, CTX);
  out_gemm<<<dim3(8, 32), 256, 0, stream>>>(CTX, W16 + (size_t)3 * DM * DM, bo, out);
}

// Round 5
// 226.228 us; speedup vs baseline: 1.0336x; 1.0336x over previous
//
#include <hip/hip_runtime.h>

// MHA: B=2, S=2048, D=1024, H=16, DK=64. All GEMMs are x @ W.T (+bias).
// R13: pivot to the non-attn ~180us. attn reverted to R11 structure (best,
//  51.5us) with R12's grid orientation (bh on x -> one bh's q-blocks share an
//  XCD; FETCH 69.7->12.4 MB proven). GEMM changes:
//  (1) grid dims swapped to (m, n, z): id%8 = m-block%8, so each XCD holds
//      4 m-panels x all n-blocks -> A-tile reused 8x inside one L2 and W
//      (2 MB) L2-resident. Old mapping spread A-reuse across all 8 XCDs.
//  (2) non-VT epilogue: MFMA operands swapped (valid: A/B frag lane layouts
//      are symmetric) so C-reg spans N -> 4 consecutive cols/lane ->
//      vectorized f16x4/float4 stores + float4 bias, 16 instead of 64 store
//      instructions per wave. VT path keeps original order.

#define S_LEN 2048
#define BATCH 2
#define DM    1024
#define NH    16
#define DKH   64
#define BS    (BATCH * S_LEN)   // 4096 rows

typedef _Float16 f16x8 __attribute__((ext_vector_type(8)));
typedef _Float16 f16x4 __attribute__((ext_vector_type(4)));
typedef _Float16 f16x2 __attribute__((ext_vector_type(2)));
typedef __fp16   h16x2 __attribute__((ext_vector_type(2)));
typedef float    f32x4 __attribute__((ext_vector_type(4)));
typedef float    f32x16 __attribute__((ext_vector_type(16)));

__device__ __forceinline__ f16x2 pk_f16(float a, float b) {
  h16x2 r = __builtin_amdgcn_cvt_pkrtz(a, b);
  return __builtin_bit_cast(f16x2, r);
}

__device__ __forceinline__ void gld16(const void* g, void* l) {
  __builtin_amdgcn_global_load_lds(
      (const __attribute__((address_space(1))) void*)g,
      (__attribute__((address_space(3))) void*)l, 16, 0, 0);
}

__device__ __forceinline__ float fast_exp2(float x) {
#if __has_builtin(__builtin_amdgcn_exp2f)
  return __builtin_amdgcn_exp2f(x);
#else
  return exp2f(x);
#endif
}

__device__ __forceinline__ int swap23(int x) {   // swap bits 2 and 3 (involution)
  return (x & ~12) | ((x & 4) << 1) | ((x & 8) >> 1);
}

// ---------------- fp32 -> fp16 conversion ----------------
__global__ __launch_bounds__(256) void cvt_all(
    const float* __restrict__ q, const float* __restrict__ k, const float* __restrict__ v,
    const float* __restrict__ wq, const float* __restrict__ wk,
    const float* __restrict__ wv, const float* __restrict__ wo,
    _Float16* __restrict__ xq, _Float16* __restrict__ xk, _Float16* __restrict__ xv,
    _Float16* __restrict__ w16)
{
  const int y = blockIdx.y;
  const float* src; _Float16* dst; int n;
  if (y == 0)      { src = q;  dst = xq; n = BS * DM; }
  else if (y == 1) { src = k;  dst = xk; n = BS * DM; }
  else if (y == 2) { src = v;  dst = xv; n = BS * DM; }
  else {
    src = (y == 3) ? wq : ((y == 4) ? wk : ((y == 5) ? wv : wo));
    dst = w16 + (size_t)(y - 3) * (DM * DM);
    n = DM * DM;
  }
  int i0 = (blockIdx.x * 256 + threadIdx.x) * 4;
  if (i0 < n) {
    float4 f = *(const float4*)(src + i0);
    f16x2 lo = pk_f16(f.x, f.y);
    f16x2 hi = pk_f16(f.z, f.w);
    f16x4 hh; hh[0] = lo[0]; hh[1] = lo[1]; hh[2] = hi[0]; hh[3] = hi[1];
    *(f16x4*)(dst + i0) = hh;
  }
}

// ---------------- 128x128-tile GEMM: C = (A @ W^T + bias)*oscale ----------------
// grid (m-blocks, n-blocks[, z]) -- m fastest so id%8 = m%8 (XCD gets 4
// m-panels x all n: A-tiles L2-reused 8x, W panel L2-resident).
// VT=false: operand-swapped MFMA -> C-reg spans N -> vectorized stores.
template <typename OUT_T, bool VT>
__device__ __forceinline__ void gemm_core(
    const _Float16* __restrict__ A, const _Float16* __restrict__ W,
    const float* __restrict__ bias, OUT_T* __restrict__ out, float oscale)
{
  const int tid  = threadIdx.x;
  const int l    = tid & 63;
  const int wv   = tid >> 6;
  const int c    = l & 15, quad = l >> 4;
  const int m0   = blockIdx.x * 128, n0 = blockIdx.y * 128;
  const int wm   = wv & 1, wn = wv >> 1;
  __shared__ _Float16 sA[128 * 64];
  __shared__ _Float16 sB[128 * 64];

  const _Float16* gA[4]; const _Float16* gB[4];
#pragma unroll
  for (int p = 0; p < 4; ++p) {
    int s = tid + p * 256, r = s >> 3, g = (s & 7) ^ (r & 7);
    gA[p] = A + (size_t)(m0 + r) * DM + g * 8;
    gB[p] = W + (size_t)(n0 + r) * DM + g * 8;
  }
  const int cx = c & 7;

  // VT: acc[i][j] (reg spans M).  !VT: acc[j][i] with swapped operands
  // (reg spans N -> 4 consecutive output cols per lane).
  f32x4 acc[4][4] = {};
  for (int k0 = 0; k0 < DM; k0 += 64) {
    __syncthreads();
#pragma unroll
    for (int p = 0; p < 4; ++p) {
      gld16(gA[p] + k0, sA + (tid + p * 256) * 8);
      gld16(gB[p] + k0, sB + (tid + p * 256) * 8);
    }
    __syncthreads();
#pragma unroll
    for (int ks = 0; ks < 2; ++ks) {
      f16x8 af[4], bf[4];
#pragma unroll
      for (int i = 0; i < 4; ++i)
        af[i] = *(const f16x8*)&sA[(wm * 64 + i * 16 + c) * 64 + ((ks * 4 + quad) ^ cx) * 8];
#pragma unroll
      for (int j = 0; j < 4; ++j)
        bf[j] = *(const f16x8*)&sB[(wn * 64 + j * 16 + c) * 64 + ((ks * 4 + quad) ^ cx) * 8];
#pragma unroll
      for (int i = 0; i < 4; ++i)
#pragma unroll
        for (int j = 0; j < 4; ++j) {
          if constexpr (VT)
            acc[i][j] = __builtin_amdgcn_mfma_f32_16x16x32_f16(af[i], bf[j], acc[i][j], 0, 0, 0);
          else
            acc[j][i] = __builtin_amdgcn_mfma_f32_16x16x32_f16(bf[j], af[i], acc[j][i], 0, 0, 0);
        }
    }
  }
  if constexpr (VT) {
#pragma unroll
    for (int j = 0; j < 4; ++j) {
      int col = n0 + wn * 64 + j * 16 + c;
      float bb = bias[col];
      int hh = col >> 6, dd = col & 63;
#pragma unroll
      for (int i = 0; i < 4; ++i) {
        int row = m0 + wm * 64 + i * 16 + quad * 4;
        int bb2 = row >> 11, ss = row & (S_LEN - 1);
        _Float16* dst = (_Float16*)out + ((size_t)(bb2 * NH + hh) * DKH + dd) * S_LEN + ss;
        f16x4 v4;
#pragma unroll
        for (int r = 0; r < 4; ++r) v4[r] = (_Float16)((acc[i][j][r] + bb) * oscale);
        *(f16x4*)dst = v4;
      }
    }
  } else {
    // acc[j][i][r] = C[m = m0+wm*64+i*16+c][n = n0+wn*64+j*16+quad*4+r]
#pragma unroll
    for (int j = 0; j < 4; ++j) {
      const int nb = n0 + wn * 64 + j * 16 + quad * 4;
      const f32x4 bb = *(const f32x4*)(bias + nb);
#pragma unroll
      for (int i = 0; i < 4; ++i) {
        const int m = m0 + wm * 64 + i * 16 + c;
        if constexpr (__is_same(OUT_T, float)) {
          f32x4 v4;
#pragma unroll
          for (int r = 0; r < 4; ++r) v4[r] = (acc[j][i][r] + bb[r]) * oscale;
          *(f32x4*)((float*)out + (size_t)m * DM + nb) = v4;
        } else {
          f16x4 v4;
#pragma unroll
          for (int r = 0; r < 4; ++r) v4[r] = (_Float16)((acc[j][i][r] + bb[r]) * oscale);
          *(f16x4*)((_Float16*)out + (size_t)m * DM + nb) = v4;
        }
      }
    }
  }
}

#define SC_Q (0.125f * 1.44269504088896340736f)   // 1/sqrt(64) * log2(e)

__global__ __launch_bounds__(256) void proj3(
    const _Float16* __restrict__ xq, const _Float16* __restrict__ xk,
    const _Float16* __restrict__ xv, const _Float16* __restrict__ w16,
    const float* __restrict__ bq, const float* __restrict__ bk, const float* __restrict__ bv,
    _Float16* __restrict__ Q, _Float16* __restrict__ K, _Float16* __restrict__ Vt)
{
  const int z = blockIdx.z;
  if (z == 2) {
    gemm_core<_Float16, true>(xv, w16 + (size_t)2 * DM * DM, bv, Vt, 1.0f);
  } else if (z == 0) {
    gemm_core<_Float16, false>(xq, w16, bq, Q, SC_Q);
  } else {
    gemm_core<_Float16, false>(xk, w16 + (size_t)DM * DM, bk, K, 1.0f);
  }
}

__global__ __launch_bounds__(256) void out_gemm(
    const _Float16* __restrict__ ctx, const _Float16* __restrict__ wo,
    const float* __restrict__ bo, float* __restrict__ out)
{
  gemm_core<float, false>(ctx, wo, bo, out, 1.0f);
}

// ---------------- fused flash attention (32x32 MFMA, register-resident P) -----
// R13 = R11 structure (best: 51.5us, conflicts 2.1M) with R12's grid
// orientation: grid (B*H, S/128) = (32, 16), bh fastest -> one bh's q-blocks
// share an XCD (FETCH 69.7 -> ~12 MB proven in R12).
// 4 waves = (wq in 2) x (wk in 2); wave owns 64 q-rows x 32 keys/iter.
// Shared double-buffered K/V tiles, 1 barrier point per iter.
__global__ __launch_bounds__(256, 2) void attn(
    const _Float16* __restrict__ Q, const _Float16* __restrict__ K,
    const _Float16* __restrict__ Vt, _Float16* __restrict__ ctx)
{
  const int tid = threadIdx.x;
  const int l   = tid & 63, wv = tid >> 6;
  const int lo5 = l & 31, hf = l >> 5;
  const int wq  = wv >> 1, wk = wv & 1;
  const int bh  = blockIdx.x;          // XCD-local: id%8 == bh%8
  const int q0  = blockIdx.y * 128;
  const int b   = bh >> 4, hd = bh & 15;
  __shared__ _Float16 sK[2][64 * 64];   // [slot-row][d], swizzled 16B blocks, rows permuted by swap23
  __shared__ _Float16 sV[2][64 * 64];   // [d][key], swizzled 16B blocks, natural

  // persistent Q B-frags: qf[qb][kc] = Q[q = q0+wq*64+qb*32+lo5][d = 16*kc+8*hf ..+8]
  f16x8 qf0[4], qf1[4];
  {
    const _Float16* Qg0 = Q + ((size_t)(b * S_LEN + q0 + wq * 64 + lo5)) * DM + hd * DKH + 8 * hf;
    const _Float16* Qg1 = Qg0 + (size_t)32 * DM;
#pragma unroll
    for (int kc = 0; kc < 4; ++kc) { qf0[kc] = *(const f16x8*)(Qg0 + 16 * kc);
                                     qf1[kc] = *(const f16x8*)(Qg1 + 16 * kc); }
  }

  f32x16 o0[2] = {}, o1[2] = {};
  float l0 = 0.f, l1 = 0.f;
  const f16x2 ones = {(_Float16)1.0f, (_Float16)1.0f};

  const _Float16* Kg0 = K + ((size_t)b * S_LEN) * DM + hd * DKH;
  const _Float16* Vg0 = Vt + ((size_t)bh * DKH) * S_LEN;

  // staging: 512 16B slots per tile per array; thread handles slots {tid, tid+256}.
  // slot s: LDS block s (linear); row r=s>>3; global block (s&7)^(r&7).
  // K global row = swap23(r) (row permutation); V rows are d (natural).
  const int sa = tid,       ra = sa >> 3, ba = (sa & 7) ^ (ra & 7);
  const int sb = tid + 256, rb = sb >> 3, bb = (sb & 7) ^ (rb & 7);
  const _Float16* gKa = Kg0 + (size_t)swap23(ra) * DM + ba * 8;
  const _Float16* gKb = Kg0 + (size_t)swap23(rb) * DM + bb * 8;
  const _Float16* gVa = Vg0 + (size_t)ra * S_LEN + ba * 8;
  const _Float16* gVb = Vg0 + (size_t)rb * S_LEN + bb * 8;
  const int rx = lo5 & 7;   // frag-read block xor (row & 7)

#define STAGE(t, bf) do {                                   \
    const size_t k0s = (size_t)(t) * 64;                    \
    gld16(gKa + k0s * DM, sK[bf] + sa * 8);                 \
    gld16(gKb + k0s * DM, sK[bf] + sb * 8);                 \
    gld16(gVa + k0s,      sV[bf] + sa * 8);                 \
    gld16(gVb + k0s,      sV[bf] + sb * 8);                 \
  } while (0)

  // prologue: tile 0 -> buf 0, drain, publish
  STAGE(0, 0);
  asm volatile("s_waitcnt vmcnt(0)" ::: "memory");
  __builtin_amdgcn_s_barrier();

  const int NT = S_LEN / 64;
  for (int kt = 0; kt < NT; ++kt) {
    const int cur = kt & 1;
    if (kt + 1 < NT) STAGE(kt + 1, cur ^ 1);

    const _Float16* sKc = sK[cur];
    const _Float16* sVc = sV[cur];

    // S^T for wk's 32-key block vs both q-blocks: one kf read feeds 2 mfma.
    f32x16 sA0 = {}, sA1 = {};
    __builtin_amdgcn_s_setprio(1);
#pragma unroll
    for (int kc = 0; kc < 4; ++kc) {
      f16x8 kf = *(const f16x8*)&sKc[(32 * wk + lo5) * 64 + ((2 * kc + hf) ^ rx) * 8];
      sA0 = __builtin_amdgcn_mfma_f32_32x32x16_f16(kf, qf0[kc], sA0, 0, 0, 0);
      sA1 = __builtin_amdgcn_mfma_f32_32x32x16_f16(kf, qf1[kc], sA1, 0, 0, 0);
    }
    __builtin_amdgcn_s_setprio(0);

    // P = 2^S, packed fp16 in C-reg order -> direct PV A-operand (swap23).
    f16x8 p0[2], p1[2];
#pragma unroll
    for (int half = 0; half < 2; ++half)
#pragma unroll
      for (int j2 = 0; j2 < 4; ++j2) {
        float a0 = fast_exp2(sA0[8 * half + 2 * j2]);
        float a1 = fast_exp2(sA0[8 * half + 2 * j2 + 1]);
        f16x2 pka = pk_f16(a0, a1);
        p0[half][2 * j2]     = pka[0];
        p0[half][2 * j2 + 1] = pka[1];
        l0 = __builtin_amdgcn_fdot2(__builtin_bit_cast(h16x2, pka),
                                    __builtin_bit_cast(h16x2, ones), l0, false);
        float b0 = fast_exp2(sA1[8 * half + 2 * j2]);
        float b1 = fast_exp2(sA1[8 * half + 2 * j2 + 1]);
        f16x2 pkb = pk_f16(b0, b1);
        p1[half][2 * j2]     = pkb[0];
        p1[half][2 * j2 + 1] = pkb[1];
        l1 = __builtin_amdgcn_fdot2(__builtin_bit_cast(h16x2, pkb),
                                    __builtin_bit_cast(h16x2, ones), l1, false);
      }

    // PV: one vf read feeds both q-blocks' O accumulators.
    __builtin_amdgcn_s_setprio(1);
#pragma unroll
    for (int db = 0; db < 2; ++db)
#pragma unroll
      for (int half = 0; half < 2; ++half) {
        const int kc2 = 2 * wk + half;
        f16x8 vf = *(const f16x8*)&sVc[(32 * db + lo5) * 64 + ((2 * kc2 + hf) ^ rx) * 8];
        o0[db] = __builtin_amdgcn_mfma_f32_32x32x16_f16(p0[half], vf, o0[db], 0, 0, 0);
        o1[db] = __builtin_amdgcn_mfma_f32_32x32x16_f16(p1[half], vf, o1[db], 0, 0, 0);
      }
    __builtin_amdgcn_s_setprio(0);

    if (kt + 1 < NT) {
      asm volatile("s_waitcnt vmcnt(0)" ::: "memory");
      __builtin_amdgcn_s_barrier();
    }
  }
#undef STAGE

  __syncthreads();   // compute done; LDS buffers dead -> merge scratch

  // per-wave row sums (partial over wk's 32 keys), combined across halves
  l0 += __shfl_xor(l0, 32);
  l1 += __shfl_xor(l1, 32);
  float* lbuf = (float*)&sV[0][0];     // [wq][qb][wk][32] = 256 floats (in sV, kept)
  float* obuf = (float*)&sK[0][0];     // 16 KB f32 scratch per db pass (all of sK)
  if (hf == 0) {
    lbuf[((wq * 2 + 0) * 2 + wk) * 32 + lo5] = l0;
    lbuf[((wq * 2 + 1) * 2 + wk) * 32 + lo5] = l1;
  }
  __syncthreads();

  // inverse row sums (both q-blocks), valid for all waves
  float inv0[16], inv1[16];
#pragma unroll
  for (int r = 0; r < 16; ++r) {
    int qq = 8 * (r >> 2) + 4 * hf + (r & 3);
    inv0[r] = 1.0f / (lbuf[((wq * 2 + 0) * 2 + 0) * 32 + qq] +
                      lbuf[((wq * 2 + 0) * 2 + 1) * 32 + qq]);
    inv1[r] = 1.0f / (lbuf[((wq * 2 + 1) * 2 + 0) * 32 + qq] +
                      lbuf[((wq * 2 + 1) * 2 + 1) * 32 + qq]);
  }

  _Float16* Og = ctx + ((size_t)(b * S_LEN + q0 + wq * 64)) * DM + hd * DKH;
#pragma unroll
  for (int db = 0; db < 2; ++db) {
    // pass: wk==1 publishes its partial o[.][db]; wk==0 adds + stores
    if (wk == 1) {
#pragma unroll
      for (int r = 0; r < 16; ++r) {
        int qq = 8 * (r >> 2) + 4 * hf + (r & 3);
        obuf[((wq * 2 + 0) * 32 + qq) * 32 + lo5] = o0[db][r];
        obuf[((wq * 2 + 1) * 32 + qq) * 32 + lo5] = o1[db][r];
      }
    }
    __syncthreads();
    if (wk == 0) {
#pragma unroll
      for (int r = 0; r < 16; ++r) {
        int qq = 8 * (r >> 2) + 4 * hf + (r & 3);
        float v0 = o0[db][r] + obuf[((wq * 2 + 0) * 32 + qq) * 32 + lo5];
        float v1 = o1[db][r] + obuf[((wq * 2 + 1) * 32 + qq) * 32 + lo5];
        Og[(size_t)qq * DM + 32 * db + lo5]        = (_Float16)(v0 * inv0[r]);
        Og[(size_t)(32 + qq) * DM + 32 * db + lo5] = (_Float16)(v1 * inv1[r]);
      }
    }
    __syncthreads();   // obuf free for next db pass
  }
}

extern "C" void kernel_launch(void* const* d_in, const int* in_sizes, int n_in,
                              void* d_out, int out_size, void* d_ws, size_t ws_size,
                              hipStream_t stream)
{
  (void)in_sizes; (void)n_in; (void)out_size; (void)ws_size;
  const float* q  = (const float*)d_in[0];
  const float* k  = (const float*)d_in[1];
  const float* v  = (const float*)d_in[2];
  const float* wq = (const float*)d_in[3];
  const float* bq = (const float*)d_in[4];
  const float* wk = (const float*)d_in[5];
  const float* bk = (const float*)d_in[6];
  const float* wv = (const float*)d_in[7];
  const float* bv = (const float*)d_in[8];
  const float* wo = (const float*)d_in[9];
  const float* bo = (const float*)d_in[10];

  char* ws = (char*)d_ws;
  _Float16* XQ  = (_Float16*)(ws);                    // dead after proj3 -> CTX
  _Float16* XK  = (_Float16*)(ws + (8u  << 20));
  _Float16* XV  = (_Float16*)(ws + (16u << 20));
  _Float16* W16 = (_Float16*)(ws + (24u << 20));      // Wq,Wk,Wv,Wo
  _Float16* Qp  = (_Float16*)(ws + (32u << 20));
  _Float16* Kp  = (_Float16*)(ws + (40u << 20));
  _Float16* VT  = (_Float16*)(ws + (48u << 20));      // proj3 writes transposed V here
  _Float16* CTX = XQ;
  float* out = (float*)d_out;

  cvt_all<<<dim3(4096, 7), 256, 0, stream>>>(q, k, v, wq, wk, wv, wo, XQ, XK, XV, W16);
  proj3<<<dim3(32, 8, 3), 256, 0, stream>>>(XQ, XK, XV, W16, bq, bk, bv, Qp, Kp, VT);
  attn<<<dim3(32, 16), 256, 0, stream>>>(Qp, Kp, VT, CTX);
  out_gemm<<<dim3(32, 8), 256, 0, stream>>>(CTX, W16 + (size_t)3 * DM * DM, bo, out);
}